// Round 2
// baseline (54.769 us; speedup 1.0000x reference)
//
#include <hip/hip_runtime.h>
#include <math.h>

#define NKEYS 8192
#define NBINS 128
#define NFREQ 64
#define NKER  3
#define HEADD (2 * NFREQ)

#define KPB     16            // keys per block
#define THREADS 512           // 128 bins x 4 key-quarters
#define KPT     (KPB / 4)     // keys per thread = 4
#define KV_STRIDE (KPB + 1)   // pad to break bank conflicts on prologue writes

#define FT      4                       // freqs per P-tile
#define NT      (NFREQ / FT)            // 16 tiles
#define TILE_F4 (FT * NKER * NBINS)     // 1536 float4 = 24 KB per tile

#if __has_builtin(__builtin_amdgcn_exp2f)
#define EXP2(x) __builtin_amdgcn_exp2f(x)
#else
#define EXP2(x) exp2f(x)
#endif

#define LOG2E 1.44269504088896340736f

typedef float v2f __attribute__((ext_vector_type(2)));

static __device__ inline v2f fma2(v2f a, v2f b, v2f c) {
#if __has_builtin(__builtin_elementwise_fma)
    return __builtin_elementwise_fma(a, b, c);
#else
    v2f r; r.x = fmaf(a.x, b.x, c.x); r.y = fmaf(a.y, b.y, c.y); return r;
#endif
}

// ---------------------------------------------------------------------------
// Kernel 1: precompute per-(b,f,k) params into d_ws as float4:
//   { ka*cos(mu_eff), ka*sin(mu_eff), -ka, weight }  with ka = kappa*log2(e)
// layout [f][k][b] so main-kernel per-bin reads are lane-consecutive.
// ---------------------------------------------------------------------------
__global__ void precompute_params(const float* __restrict__ refang,
                                  const float* __restrict__ mu,
                                  const float* __restrict__ kappa,
                                  const float* __restrict__ weight,
                                  float4* __restrict__ P) {
    int o = blockIdx.x * blockDim.x + threadIdx.x;
    if (o >= NBINS * NFREQ * NKER) return;
    int b = o & (NBINS - 1);
    int fk = o >> 7;
    int f = fk / NKER;
    int k = fk - f * NKER;
    int in_idx = (b * NFREQ + f) * NKER + k;
    float me = mu[in_idx] + refang[f];          // |me| < ~5 rad: fast sincos ok
    float ka = kappa[in_idx] * LOG2E;
    float s, c;
    __sincosf(me, &s, &c);
    P[o] = make_float4(ka * c, ka * s, -ka, weight[in_idx]);
}

// ---------------------------------------------------------------------------
// Kernel 2 (main, PRECOMP path): 16 keys x 128 bins per block.
// P streamed through double-buffered LDS tiles (FT freqs each); next tile's
// global loads issued BEFORE compute (latency hides under ~570cy of math).
// Inner math packed as float2 over key-pairs -> v_pk_fma_f32 candidates.
// ---------------------------------------------------------------------------
__global__ __launch_bounds__(THREADS) void vonmises_tiled(
    const float* __restrict__ K,
    const float4* __restrict__ P,
    const float* __restrict__ bias,
    float* __restrict__ out)
{
    __shared__ float4 kvlds[NFREQ * KV_STRIDE];   // {cx, sy, mag, 0}  (17408 B)
    __shared__ float4 pbuf[2 * TILE_F4];          // double-buffered P  (49152 B)

    const int tid  = threadIdx.x;
    const int key0 = blockIdx.x * KPB;

    // Stage kv: 16 keys x 64 freqs, coalesced float2 loads of K.
    for (int p = tid; p < KPB * NFREQ; p += THREADS) {
        int key = p >> 6;
        int f   = p & (NFREQ - 1);
        const float2 xy = *(const float2*)(K + (size_t)(key0 + key) * HEADD + 2 * f);
        float m2 = xy.x * xy.x + xy.y * xy.y;
        float rm = (m2 > 0.f) ? rsqrtf(m2) : 0.f;
        kvlds[f * KV_STRIDE + key] = make_float4(xy.x * rm, xy.y * rm, m2 * rm, 0.f);
    }

    // Tile 0: load to regs, write to buf0 (visibility via the same barrier).
    float4 st[NKER];
    #pragma unroll
    for (int c = 0; c < NKER; ++c) st[c] = P[c * THREADS + tid];
    #pragma unroll
    for (int c = 0; c < NKER; ++c) pbuf[c * THREADS + tid] = st[c];
    __syncthreads();

    const int bin   = tid & (NBINS - 1);
    const int kbase = (tid >> 7) * KPT;     // quarter * 4

    v2f accA = {0.f, 0.f}, accB = {0.f, 0.f};
    int cur = 0;

    for (int t = 0; t < NT; ++t) {
        // Issue next tile's global loads EARLY (hide L2/HBM latency under compute).
        if (t + 1 < NT) {
            const float4* src = P + (t + 1) * TILE_F4;
            #pragma unroll
            for (int c = 0; c < NKER; ++c) st[c] = src[c * THREADS + tid];
        }

        const float4* pb = pbuf + cur * TILE_F4;
        #pragma unroll
        for (int ft = 0; ft < FT; ++ft) {
            const float4* kvp = kvlds + (t * FT + ft) * KV_STRIDE + kbase;
            float4 kv0 = kvp[0], kv1 = kvp[1], kv2 = kvp[2], kv3 = kvp[3];
            v2f xA = {kv0.x, kv1.x}, yA = {kv0.y, kv1.y}, mA = {kv0.z, kv1.z};
            v2f xB = {kv2.x, kv3.x}, yB = {kv2.y, kv3.y}, mB = {kv2.z, kv3.z};
            v2f wkA = {0.f, 0.f}, wkB = {0.f, 0.f};
            #pragma unroll
            for (int k = 0; k < NKER; ++k) {
                float4 pp = pb[(ft * NKER + k) * NBINS + bin];  // lane-consecutive LDS
                v2f px = {pp.x, pp.x}, py = {pp.y, pp.y};
                v2f pz = {pp.z, pp.z}, pw = {pp.w, pp.w};
                v2f tA = fma2(xA, px, fma2(yA, py, pz));
                v2f tB = fma2(xB, px, fma2(yB, py, pz));
                v2f eA = {EXP2(tA.x), EXP2(tA.y)};
                v2f eB = {EXP2(tB.x), EXP2(tB.y)};
                wkA = fma2(eA, pw, wkA);
                wkB = fma2(eB, pw, wkB);
            }
            accA = fma2(wkA, mA, accA);    // fold magnitude once per f
            accB = fma2(wkB, mB, accB);
        }

        // Write next tile into the other buffer (its last readers were in
        // iteration t-1, protected by that iteration's barrier).
        if (t + 1 < NT) {
            float4* dst = pbuf + (cur ^ 1) * TILE_F4;
            #pragma unroll
            for (int c = 0; c < NKER; ++c) dst[c * THREADS + tid] = st[c];
        }
        __syncthreads();
        cur ^= 1;
    }

    const float bb = bias[bin];
    out[(size_t)(key0 + kbase + 0) * NBINS + bin] = accA.x + bb;
    out[(size_t)(key0 + kbase + 1) * NBINS + bin] = accA.y + bb;
    out[(size_t)(key0 + kbase + 2) * NBINS + bin] = accB.x + bb;
    out[(size_t)(key0 + kbase + 3) * NBINS + bin] = accB.y + bb;
}

// ---------------------------------------------------------------------------
// Fallback (ws too small): round-1 structure, trig inline. Correct, slower.
// ---------------------------------------------------------------------------
__global__ __launch_bounds__(THREADS) void vonmises_fallback(
    const float* __restrict__ K,
    const float* __restrict__ refang,
    const float* __restrict__ mu,
    const float* __restrict__ kappa,
    const float* __restrict__ weight,
    const float* __restrict__ bias,
    float* __restrict__ out)
{
    __shared__ float4 kvlds[NFREQ * KV_STRIDE];

    const int tid  = threadIdx.x;
    const int key0 = blockIdx.x * KPB;

    for (int p = tid; p < KPB * NFREQ; p += THREADS) {
        int key = p >> 6;
        int f   = p & (NFREQ - 1);
        const float2 xy = *(const float2*)(K + (size_t)(key0 + key) * HEADD + 2 * f);
        float m2 = xy.x * xy.x + xy.y * xy.y;
        float rm = (m2 > 0.f) ? rsqrtf(m2) : 0.f;
        kvlds[f * KV_STRIDE + key] = make_float4(xy.x * rm, xy.y * rm, m2 * rm, 0.f);
    }
    __syncthreads();

    const int bin   = tid & (NBINS - 1);
    const int kbase = (tid >> 7) * KPT;

    float acc[KPT] = {0.f, 0.f, 0.f, 0.f};

    for (int f = 0; f < NFREQ; ++f) {
        float4 kv[KPT];
        #pragma unroll
        for (int j = 0; j < KPT; ++j) kv[j] = kvlds[f * KV_STRIDE + kbase + j];
        float wk[KPT] = {0.f, 0.f, 0.f, 0.f};
        #pragma unroll
        for (int k = 0; k < NKER; ++k) {
            int in_idx = (bin * NFREQ + f) * NKER + k;
            float me = mu[in_idx] + refang[f];
            float ka = kappa[in_idx] * LOG2E;
            float s, c;
            __sincosf(me, &s, &c);
            #pragma unroll
            for (int j = 0; j < KPT; ++j) {
                float t = fmaf(kv[j].x, ka * c, fmaf(kv[j].y, ka * s, -ka));
                wk[j] = fmaf(EXP2(t), weight[in_idx], wk[j]);
            }
        }
        #pragma unroll
        for (int j = 0; j < KPT; ++j) acc[j] = fmaf(wk[j], kv[j].z, acc[j]);
    }

    const float bb = bias[bin];
    #pragma unroll
    for (int j = 0; j < KPT; ++j)
        out[(size_t)(key0 + kbase + j) * NBINS + bin] = acc[j] + bb;
}

// ---------------------------------------------------------------------------
extern "C" void kernel_launch(void* const* d_in, const int* in_sizes, int n_in,
                              void* d_out, int out_size, void* d_ws, size_t ws_size,
                              hipStream_t stream) {
    const float* K      = (const float*)d_in[0];
    const float* refang = (const float*)d_in[1];
    const float* mu     = (const float*)d_in[2];
    const float* kappa  = (const float*)d_in[3];
    const float* weight = (const float*)d_in[4];
    const float* bias   = (const float*)d_in[5];
    float* out = (float*)d_out;

    const size_t need = (size_t)NBINS * NFREQ * NKER * sizeof(float4); // 384 KiB

    if (ws_size >= need) {
        float4* P = (float4*)d_ws;
        int total = NBINS * NFREQ * NKER;
        precompute_params<<<(total + 255) / 256, 256, 0, stream>>>(refang, mu, kappa, weight, P);
        vonmises_tiled<<<NKEYS / KPB, THREADS, 0, stream>>>(K, P, bias, out);
    } else {
        vonmises_fallback<<<NKEYS / KPB, THREADS, 0, stream>>>(
            K, refang, mu, kappa, weight, bias, out);
    }
}

// Round 3
// 19.102 us; speedup vs baseline: 2.8671x; 2.8671x over previous
//
#include <hip/hip_runtime.h>
#include <math.h>

#define NKEYS 8192
#define NBINS 128
#define NFREQ 64
#define NKER  3
#define HEADD 128

// Fourier expansion order: e^{k(cos d - 1)} = e^-k [I0 + 2 sum_m Im cos(m d)]
// kappa <= 1 -> I7(1)/e ~ 8e-7: truncation negligible at M=6.
#define MHARM 6
#define NCH   (2 * MHARM + 1)     // 13 channels per freq: {1, cos m, sin m}
#define KDIM  (NCH * NFREQ)       // 832 = 26 * 32
#define KSTEPS (KDIM / 32)        // 26 MFMA K-steps

typedef _Float16 f16x8 __attribute__((ext_vector_type(8)));
typedef float    f32x4 __attribute__((ext_vector_type(4)));

// ---------------------------------------------------------------------------
// Kernel A: coefficient table Bt[bin][kd], kd = ch*64 + f, fp16.
//   ch0      <- sum_k w e^-k I0(k)
//   ch(2m-1) <- sum_k 2 w e^-k Im(k) cos(m*mu_eff)
//   ch(2m)   <- sum_k 2 w e^-k Im(k) sin(m*mu_eff)
// 8192 threads, ~60 flops each + sincos/exp: ~2 us.
// ---------------------------------------------------------------------------
__global__ void build_coeffs(const float* __restrict__ refang,
                             const float* __restrict__ mu,
                             const float* __restrict__ kappa,
                             const float* __restrict__ weight,
                             _Float16* __restrict__ Bt) {
    int gid = blockIdx.x * blockDim.x + threadIdx.x;
    if (gid >= NBINS * NFREQ) return;
    int b = gid >> 6, f = gid & 63;
    float rf = refang[f];

    float acc[NCH];
    #pragma unroll
    for (int c = 0; c < NCH; ++c) acc[c] = 0.f;

    for (int k = 0; k < NKER; ++k) {
        int idx = (b * NFREQ + f) * NKER + k;
        float me  = mu[idx] + rf;
        float kap = kappa[idx];
        float w   = weight[idx];
        float h = 0.5f * kap, h2 = h * h;
        float wek = w * expf(-kap);
        float c1, s1;
        sincosf(me, &s1, &c1);

        // modified Bessel I_0..I_M via series (x<=1: 7 terms -> ~1e-12)
        float Im[MHARM + 1];
        float tm = 1.f;                       // h^m / m!
        #pragma unroll
        for (int m = 0; m <= MHARM; ++m) {
            float t = tm, s = tm;
            #pragma unroll
            for (int j = 1; j <= 6; ++j) { t *= h2 / (float)(j * (m + j)); s += t; }
            Im[m] = s;
            tm *= h / (float)(m + 1);
        }

        acc[0] += wek * Im[0];
        float cp = 1.f, sp = 0.f, cc = c1, sc = s1;  // cos/sin(m*me) recurrence
        #pragma unroll
        for (int m = 1; m <= MHARM; ++m) {
            float g = 2.f * wek * Im[m];
            acc[2 * m - 1] += g * cc;
            acc[2 * m]     += g * sc;
            float cn = fmaf(2.f * c1, cc, -cp);
            float sn = fmaf(2.f * c1, sc, -sp);
            cp = cc; sp = sc; cc = cn; sc = sn;
        }
    }
    #pragma unroll
    for (int c = 0; c < NCH; ++c)
        Bt[(size_t)b * KDIM + c * NFREQ + f] = (_Float16)acc[c];   // lane-consecutive f
}

// ---------------------------------------------------------------------------
// Kernel B: fused features + MFMA GEMM.
// Block: 32 rows x all 128 cols, 512 threads (8 waves x 16 cols).
// Prologue builds A-tile At[32][832] fp16 in LDS from K (Chebyshev harmonics,
// no transcendentals). K-loop: 26 steps of 16x16x32 f16 MFMA, Bt streamed
// from L2 (208 KB, resident), no barriers in loop.
// ---------------------------------------------------------------------------
#define BM 32
#define GTHREADS 512
#define APAD 8                     // +8 halfs: row stride 1680 B -> bank spread
#define ASTR (KDIM + APAD)         // 840

__global__ __launch_bounds__(GTHREADS) void fused_gemm(
    const float* __restrict__ K,
    const _Float16* __restrict__ Bt,
    const float* __restrict__ bias,
    float* __restrict__ out)
{
    __shared__ __align__(16) _Float16 At[BM][ASTR];   // 53,760 B

    const int tid  = threadIdx.x;
    const int row0 = blockIdx.x * BM;

    // --- features: 2048 (n,f) pairs, 4 per thread, coalesced float2 loads ---
    for (int p = tid; p < BM * NFREQ; p += GTHREADS) {
        int n = p >> 6, f = p & 63;
        const float2 xy = *(const float2*)(K + (size_t)(row0 + n) * HEADD + 2 * f);
        float m2   = xy.x * xy.x + xy.y * xy.y;
        float rinv = (m2 > 0.f) ? rsqrtf(m2) : 0.f;
        float mag  = m2 * rinv;
        float c1   = xy.x * rinv, s1 = xy.y * rinv;
        At[n][f] = (_Float16)mag;
        float cp = 1.f, sp = 0.f, cc = c1, sc = s1;
        #pragma unroll
        for (int m = 1; m <= MHARM; ++m) {
            At[n][(2 * m - 1) * NFREQ + f] = (_Float16)(mag * cc);
            At[n][(2 * m) * NFREQ + f]     = (_Float16)(mag * sc);
            float cn = fmaf(2.f * c1, cc, -cp);
            float sn = fmaf(2.f * c1, sc, -sp);
            cp = cc; sp = sc; cc = cn; sc = sn;
        }
    }
    __syncthreads();

    // --- GEMM: wave w covers cols w*16..w*16+15; 2 M-halves of 16 rows ---
    const int lane = tid & 63, wave = tid >> 6;
    const int lc = lane & 15, q = lane >> 4;
    const int col = wave * 16 + lc;

    f32x4 acc0 = {0.f, 0.f, 0.f, 0.f};
    f32x4 acc1 = {0.f, 0.f, 0.f, 0.f};

    const _Float16* bp = Bt + (size_t)col * KDIM + q * 8;
    #pragma unroll
    for (int kt = 0; kt < KSTEPS; ++kt) {
        const int k0 = kt * 32 + q * 8;
        f16x8 a0 = *(const f16x8*)&At[lc][k0];
        f16x8 a1 = *(const f16x8*)&At[16 + lc][k0];
        f16x8 b  = *(const f16x8*)(bp + kt * 32);          // 64B-coalesced per col
        acc0 = __builtin_amdgcn_mfma_f32_16x16x32_f16(a0, b, acc0, 0, 0, 0);
        acc1 = __builtin_amdgcn_mfma_f32_16x16x32_f16(a1, b, acc1, 0, 0, 0);
    }

    // C/D layout (m89-verified): col = lane&15, row = (lane>>4)*4 + reg
    const float bb = bias[col];
    #pragma unroll
    for (int j = 0; j < 4; ++j) {
        out[(size_t)(row0 + q * 4 + j) * NBINS + col]      = acc0[j] + bb;
        out[(size_t)(row0 + 16 + q * 4 + j) * NBINS + col] = acc1[j] + bb;
    }
}

// ---------------------------------------------------------------------------
// Fallback (ws too small for Bt): direct form, inline trig. Correct, slow.
// ---------------------------------------------------------------------------
#define KPB 16
#define FTHREADS 512
#define KPT 4
#define KV_STRIDE (KPB + 1)
#define LOG2E 1.44269504088896340736f

__global__ __launch_bounds__(FTHREADS) void vonmises_fallback(
    const float* __restrict__ K,
    const float* __restrict__ refang,
    const float* __restrict__ mu,
    const float* __restrict__ kappa,
    const float* __restrict__ weight,
    const float* __restrict__ bias,
    float* __restrict__ out)
{
    __shared__ float4 kvlds[NFREQ * KV_STRIDE];
    const int tid  = threadIdx.x;
    const int key0 = blockIdx.x * KPB;

    for (int p = tid; p < KPB * NFREQ; p += FTHREADS) {
        int key = p >> 6, f = p & (NFREQ - 1);
        const float2 xy = *(const float2*)(K + (size_t)(key0 + key) * HEADD + 2 * f);
        float m2 = xy.x * xy.x + xy.y * xy.y;
        float rm = (m2 > 0.f) ? rsqrtf(m2) : 0.f;
        kvlds[f * KV_STRIDE + key] = make_float4(xy.x * rm, xy.y * rm, m2 * rm, 0.f);
    }
    __syncthreads();

    const int bin = tid & (NBINS - 1);
    const int kbase = (tid >> 7) * KPT;
    float acc[KPT] = {0.f, 0.f, 0.f, 0.f};

    for (int f = 0; f < NFREQ; ++f) {
        float4 kv[KPT];
        #pragma unroll
        for (int j = 0; j < KPT; ++j) kv[j] = kvlds[f * KV_STRIDE + kbase + j];
        float wk[KPT] = {0.f, 0.f, 0.f, 0.f};
        #pragma unroll
        for (int k = 0; k < NKER; ++k) {
            int idx = (bin * NFREQ + f) * NKER + k;
            float me = mu[idx] + refang[f];
            float ka = kappa[idx] * LOG2E;
            float s, c;
            __sincosf(me, &s, &c);
            #pragma unroll
            for (int j = 0; j < KPT; ++j) {
                float t = fmaf(kv[j].x, ka * c, fmaf(kv[j].y, ka * s, -ka));
                wk[j] = fmaf(exp2f(t), weight[idx], wk[j]);
            }
        }
        #pragma unroll
        for (int j = 0; j < KPT; ++j) acc[j] = fmaf(wk[j], kv[j].z, acc[j]);
    }
    const float bb = bias[bin];
    #pragma unroll
    for (int j = 0; j < KPT; ++j)
        out[(size_t)(key0 + kbase + j) * NBINS + bin] = acc[j] + bb;
}

// ---------------------------------------------------------------------------
extern "C" void kernel_launch(void* const* d_in, const int* in_sizes, int n_in,
                              void* d_out, int out_size, void* d_ws, size_t ws_size,
                              hipStream_t stream) {
    const float* K      = (const float*)d_in[0];
    const float* refang = (const float*)d_in[1];
    const float* mu     = (const float*)d_in[2];
    const float* kappa  = (const float*)d_in[3];
    const float* weight = (const float*)d_in[4];
    const float* bias   = (const float*)d_in[5];
    float* out = (float*)d_out;

    const size_t need = (size_t)NBINS * KDIM * sizeof(_Float16);   // 208 KiB

    if (ws_size >= need) {
        _Float16* Bt = (_Float16*)d_ws;
        build_coeffs<<<(NBINS * NFREQ + 255) / 256, 256, 0, stream>>>(
            refang, mu, kappa, weight, Bt);
        fused_gemm<<<NKEYS / BM, GTHREADS, 0, stream>>>(K, Bt, bias, out);
    } else {
        vonmises_fallback<<<NKEYS / KPB, FTHREADS, 0, stream>>>(
            K, refang, mu, kappa, weight, bias, out);
    }
}

// Round 4
// 17.135 us; speedup vs baseline: 3.1962x; 1.1148x over previous
//
#include <hip/hip_runtime.h>
#include <math.h>

#define NKEYS 8192
#define NBINS 128
#define NFREQ 64
#define NKER  3
#define HEADD 128

// Fourier expansion: e^{k(cos d - 1)} = e^-k [I0(k) + 2 sum_m Im(k) cos(m d)]
// kappa <= 1 -> truncation at M=6 is ~1e-6 relative: negligible vs fp16.
#define MHARM 6
#define NCH   (2 * MHARM + 1)     // 13 channels: {1, cos m, sin m}
#define KDIM  (NCH * NFREQ)       // 832
#define KSTEPS (KDIM / 32)        // 26 MFMA K-steps

typedef _Float16 f16x8 __attribute__((ext_vector_type(8)));
typedef float    f32x4 __attribute__((ext_vector_type(4)));

// Fragment-order index helpers (16x16x32 f16 MFMA, m89-verified layout):
//   k_global = kt*32 + q*8 + j   (q = lane>>4, j = 0..7)
//   kd = ch*64 + f  ->  kt = ch*2 + (f>>5), q = (f>>3)&3, j = f&7
#define FRAG_KT(ch, f) ((ch) * 2 + ((f) >> 5))
#define FRAG_Q(f)      (((f) >> 3) & 3)
#define FRAG_J(f)      ((f) & 7)

// ---------------------------------------------------------------------------
// Kernel A: coefficient table in B-fragment order (one contiguous 1 KB burst
// per wave per K-step in the GEMM):
//   Bswz[ ((colgrp*KSTEPS + kt)*64 + q*16 + lc)*8 + j ]  = C[col=colgrp*16+lc][kt*32+q*8+j]
// 8192 threads (one per (bin,freq)), fast trig. Total 208 KiB.
// ---------------------------------------------------------------------------
__global__ void build_coeffs(const float* __restrict__ refang,
                             const float* __restrict__ mu,
                             const float* __restrict__ kappa,
                             const float* __restrict__ weight,
                             _Float16* __restrict__ Bswz) {
    int gid = blockIdx.x * blockDim.x + threadIdx.x;
    if (gid >= NBINS * NFREQ) return;
    int b = gid >> 6, f = gid & 63;
    float rf = refang[f];

    float acc[NCH];
    #pragma unroll
    for (int c = 0; c < NCH; ++c) acc[c] = 0.f;

    #pragma unroll
    for (int k = 0; k < NKER; ++k) {
        int idx = (b * NFREQ + f) * NKER + k;
        float me  = mu[idx] + rf;
        float kap = kappa[idx];
        float w   = weight[idx];
        float h = 0.5f * kap, h2 = h * h;
        float wek = w * __expf(-kap);
        float c1, s1;
        __sincosf(me, &s1, &c1);

        // modified Bessel I_0..I_M via series (x<=1: 7 terms -> ~1e-12);
        // all divisors are compile-time constants after unrolling.
        float Im[MHARM + 1];
        float tm = 1.f;                       // h^m / m!
        #pragma unroll
        for (int m = 0; m <= MHARM; ++m) {
            float t = tm, s = tm;
            #pragma unroll
            for (int j = 1; j <= 6; ++j) { t *= h2 / (float)(j * (m + j)); s += t; }
            Im[m] = s;
            tm *= h / (float)(m + 1);
        }

        acc[0] += wek * Im[0];
        float cp = 1.f, sp = 0.f, cc = c1, sc = s1;  // cos/sin(m*me) recurrence
        #pragma unroll
        for (int m = 1; m <= MHARM; ++m) {
            float g = 2.f * wek * Im[m];
            acc[2 * m - 1] += g * cc;
            acc[2 * m]     += g * sc;
            float cn = fmaf(2.f * c1, cc, -cp);
            float sn = fmaf(2.f * c1, sc, -sp);
            cp = cc; sp = sc; cc = cn; sc = sn;
        }
    }

    const int colgrp = b >> 4, lc = b & 15;
    const int q = FRAG_Q(f), j = FRAG_J(f);
    #pragma unroll
    for (int c = 0; c < NCH; ++c) {
        int kt = FRAG_KT(c, f);
        Bswz[((size_t)(colgrp * KSTEPS + kt) * 64 + q * 16 + lc) * 8 + j] = (_Float16)acc[c];
    }
}

// ---------------------------------------------------------------------------
// Kernel B: fused features + MFMA GEMM. BM=16 rows x 128 cols per block,
// 512 threads = 8 waves, wave w -> cols [w*16, w*16+16), one f32x4 acc each.
// A-tile built in LDS in fragment order: ds_read_b128 at lane*16B, zero
// conflicts, no padding (26,624 B). B streamed from L2 in 1 KB bursts.
// ---------------------------------------------------------------------------
#define BM 16
#define GTHREADS 512

__global__ __launch_bounds__(GTHREADS) void fused_gemm(
    const float* __restrict__ K,
    const _Float16* __restrict__ Bswz,
    const float* __restrict__ bias,
    float* __restrict__ out)
{
    __shared__ __align__(16) _Float16 Afrag[KSTEPS * 64 * 8];   // 26,624 B

    const int tid  = threadIdx.x;
    const int row0 = blockIdx.x * BM;

    // --- features: 1024 (n,f) pairs, 2 per thread, coalesced float2 loads ---
    for (int p = tid; p < BM * NFREQ; p += GTHREADS) {
        int n = p >> 6, f = p & 63;
        const float2 xy = *(const float2*)(K + (size_t)(row0 + n) * HEADD + 2 * f);
        float m2   = xy.x * xy.x + xy.y * xy.y;
        float rinv = (m2 > 0.f) ? rsqrtf(m2) : 0.f;
        float mag  = m2 * rinv;
        float c1   = xy.x * rinv, s1 = xy.y * rinv;
        const int q = FRAG_Q(f), j = FRAG_J(f);
        // A row = n: addr = kt*512 + (q*16 + n)*8 + j  (halfs)
        Afrag[FRAG_KT(0, f) * 512 + (q * 16 + n) * 8 + j] = (_Float16)mag;
        float cp = 1.f, sp = 0.f, cc = c1, sc = s1;
        #pragma unroll
        for (int m = 1; m <= MHARM; ++m) {
            Afrag[FRAG_KT(2 * m - 1, f) * 512 + (q * 16 + n) * 8 + j] = (_Float16)(mag * cc);
            Afrag[FRAG_KT(2 * m, f)     * 512 + (q * 16 + n) * 8 + j] = (_Float16)(mag * sc);
            float cn = fmaf(2.f * c1, cc, -cp);
            float sn = fmaf(2.f * c1, sc, -sp);
            cp = cc; sp = sc; cc = cn; sc = sn;
        }
    }
    __syncthreads();

    const int lane = tid & 63, wave = tid >> 6;
    const int lc = lane & 15, q = lane >> 4;
    const int col = wave * 16 + lc;

    f32x4 acc = {0.f, 0.f, 0.f, 0.f};

    const f16x8* bp = (const f16x8*)Bswz + (size_t)wave * KSTEPS * 64 + lane;
    const f16x8* ap = (const f16x8*)Afrag + lane;

    #pragma unroll
    for (int kt = 0; kt < KSTEPS; ++kt) {
        f16x8 b = bp[kt * 64];        // contiguous 1 KB per wave, L2-hot
        f16x8 a = ap[kt * 64];        // ds_read_b128 at lane*16B, conflict-free
        acc = __builtin_amdgcn_mfma_f32_16x16x32_f16(a, b, acc, 0, 0, 0);
    }

    // C/D layout: col = lane&15, row = (lane>>4)*4 + reg
    const float bb = bias[col];
    #pragma unroll
    for (int j = 0; j < 4; ++j)
        out[(size_t)(row0 + q * 4 + j) * NBINS + col] = acc[j] + bb;
}

// ---------------------------------------------------------------------------
// Fallback (ws too small for Bswz): direct form, inline trig.
// ---------------------------------------------------------------------------
#define KPB 16
#define FTHREADS 512
#define KPT 4
#define KV_STRIDE (KPB + 1)
#define LOG2E 1.44269504088896340736f

__global__ __launch_bounds__(FTHREADS) void vonmises_fallback(
    const float* __restrict__ K,
    const float* __restrict__ refang,
    const float* __restrict__ mu,
    const float* __restrict__ kappa,
    const float* __restrict__ weight,
    const float* __restrict__ bias,
    float* __restrict__ out)
{
    __shared__ float4 kvlds[NFREQ * KV_STRIDE];
    const int tid  = threadIdx.x;
    const int key0 = blockIdx.x * KPB;

    for (int p = tid; p < KPB * NFREQ; p += FTHREADS) {
        int key = p >> 6, f = p & (NFREQ - 1);
        const float2 xy = *(const float2*)(K + (size_t)(key0 + key) * HEADD + 2 * f);
        float m2 = xy.x * xy.x + xy.y * xy.y;
        float rm = (m2 > 0.f) ? rsqrtf(m2) : 0.f;
        kvlds[f * KV_STRIDE + key] = make_float4(xy.x * rm, xy.y * rm, m2 * rm, 0.f);
    }
    __syncthreads();

    const int bin = tid & (NBINS - 1);
    const int kbase = (tid >> 7) * KPT;
    float acc[KPT] = {0.f, 0.f, 0.f, 0.f};

    for (int f = 0; f < NFREQ; ++f) {
        float4 kv[KPT];
        #pragma unroll
        for (int j = 0; j < KPT; ++j) kv[j] = kvlds[f * KV_STRIDE + kbase + j];
        float wk[KPT] = {0.f, 0.f, 0.f, 0.f};
        #pragma unroll
        for (int k = 0; k < NKER; ++k) {
            int idx = (bin * NFREQ + f) * NKER + k;
            float me = mu[idx] + refang[f];
            float ka = kappa[idx] * LOG2E;
            float s, c;
            __sincosf(me, &s, &c);
            #pragma unroll
            for (int j = 0; j < KPT; ++j) {
                float t = fmaf(kv[j].x, ka * c, fmaf(kv[j].y, ka * s, -ka));
                wk[j] = fmaf(exp2f(t), weight[idx], wk[j]);
            }
        }
        #pragma unroll
        for (int j = 0; j < KPT; ++j) acc[j] = fmaf(wk[j], kv[j].z, acc[j]);
    }
    const float bb = bias[bin];
    #pragma unroll
    for (int j = 0; j < KPT; ++j)
        out[(size_t)(key0 + kbase + j) * NBINS + bin] = acc[j] + bb;
}

// ---------------------------------------------------------------------------
extern "C" void kernel_launch(void* const* d_in, const int* in_sizes, int n_in,
                              void* d_out, int out_size, void* d_ws, size_t ws_size,
                              hipStream_t stream) {
    const float* K      = (const float*)d_in[0];
    const float* refang = (const float*)d_in[1];
    const float* mu     = (const float*)d_in[2];
    const float* kappa  = (const float*)d_in[3];
    const float* weight = (const float*)d_in[4];
    const float* bias   = (const float*)d_in[5];
    float* out = (float*)d_out;

    const size_t need = (size_t)NBINS * KDIM * sizeof(_Float16);   // 208 KiB

    if (ws_size >= need) {
        _Float16* Bswz = (_Float16*)d_ws;
        build_coeffs<<<NBINS * NFREQ / 64, 64, 0, stream>>>(
            refang, mu, kappa, weight, Bswz);
        fused_gemm<<<NKEYS / BM, GTHREADS, 0, stream>>>(K, Bswz, bias, out);
    } else {
        vonmises_fallback<<<NKEYS / KPB, FTHREADS, 0, stream>>>(
            K, refang, mu, kappa, weight, bias, out);
    }
}

// Round 5
// 16.178 us; speedup vs baseline: 3.3854x; 1.0592x over previous
//
#include <hip/hip_runtime.h>
#include <math.h>

#define NKEYS 8192
#define NBINS 128
#define NFREQ 64
#define NKER  3
#define HEADD 128

// Fourier expansion: e^{k(cos d - 1)} = e^-k [I0(k) + 2 sum_m Im(k) cos(m d)]
// kappa <= 1 -> truncation at M=4: 2e^-1(I5+I6+...) ~ 2.2e-4 relative, which
// summed over 192 (f,k) terms stays ~5e-3 absolute -- well under fp16 noise.
#define MHARM 4
#define NCH   (2 * MHARM + 1)     // 9 channels: {1, cos m, sin m}
#define KDIM  (NCH * NFREQ)       // 576
#define KSTEPS (KDIM / 32)        // 18 MFMA K-steps

typedef _Float16 f16x8 __attribute__((ext_vector_type(8)));
typedef _Float16 f16x4 __attribute__((ext_vector_type(4)));
typedef float    f32x4 __attribute__((ext_vector_type(4)));

// Fragment-order mapping (16x16x32 f16 MFMA, m89-verified C/D layout):
//   k_global = kt*32 + q*8 + j   (q = lane>>4, j = 0..7)
//   (ch, f) -> kt = ch*2 + (f>>5), q = (f>>3)&3, j = f&7   (bijective)
#define FRAG_KT(ch, f) ((ch) * 2 + ((f) >> 5))
#define FRAG_Q(f)      (((f) >> 3) & 3)
#define FRAG_J(f)      ((f) & 7)

// ---------------------------------------------------------------------------
// Kernel A: coefficient table in B-fragment order:
//   Bswz[ ((g*KSTEPS + kt)*64 + q*16 + lc)*8 + j ] = C[col=g*16+lc][kt*32+q*8+j]
// One thread per (bin, freq). 144 KiB total, L2-resident thereafter.
// ---------------------------------------------------------------------------
__global__ void build_coeffs(const float* __restrict__ refang,
                             const float* __restrict__ mu,
                             const float* __restrict__ kappa,
                             const float* __restrict__ weight,
                             _Float16* __restrict__ Bswz) {
    int gid = blockIdx.x * blockDim.x + threadIdx.x;
    if (gid >= NBINS * NFREQ) return;
    int b = gid >> 6, f = gid & 63;
    float rf = refang[f];

    float acc[NCH];
    #pragma unroll
    for (int c = 0; c < NCH; ++c) acc[c] = 0.f;

    #pragma unroll
    for (int k = 0; k < NKER; ++k) {
        int idx = (b * NFREQ + f) * NKER + k;
        float me  = mu[idx] + rf;
        float kap = kappa[idx];
        float w   = weight[idx];
        float h = 0.5f * kap, h2 = h * h;
        float wek = w * __expf(-kap);
        float c1, s1;
        __sincosf(me, &s1, &c1);

        // modified Bessel I_0..I_M via series (x<=1: ~1e-12)
        float Im[MHARM + 1];
        float tm = 1.f;                       // h^m / m!
        #pragma unroll
        for (int m = 0; m <= MHARM; ++m) {
            float t = tm, s = tm;
            #pragma unroll
            for (int j = 1; j <= 6; ++j) { t *= h2 / (float)(j * (m + j)); s += t; }
            Im[m] = s;
            tm *= h / (float)(m + 1);
        }

        acc[0] += wek * Im[0];
        float cp = 1.f, sp = 0.f, cc = c1, sc = s1;  // cos/sin(m*me) recurrence
        #pragma unroll
        for (int m = 1; m <= MHARM; ++m) {
            float g = 2.f * wek * Im[m];
            acc[2 * m - 1] += g * cc;
            acc[2 * m]     += g * sc;
            float cn = fmaf(2.f * c1, cc, -cp);
            float sn = fmaf(2.f * c1, sc, -sp);
            cp = cc; sp = sc; cc = cn; sc = sn;
        }
    }

    const int g = b >> 4, lc = b & 15;
    const int q = FRAG_Q(f), j = FRAG_J(f);
    #pragma unroll
    for (int c = 0; c < NCH; ++c) {
        int kt = FRAG_KT(c, f);
        Bswz[((size_t)(g * KSTEPS + kt) * 64 + q * 16 + lc) * 8 + j] = (_Float16)acc[c];
    }
}

// ---------------------------------------------------------------------------
// Kernel B: fused features + MFMA GEMM.
// Block = 32 rows x 64 cols, 256 threads = 4 waves; wave w -> 16 cols,
// TWO independent accumulators (row-chunks 0-15, 16-31) sharing each
// B-fragment: breaks the serial MFMA chain and halves B traffic.
// A built in LDS in fragment order (two 16-row chunks, 36,864 B -> 4 blk/CU).
// __launch_bounds__(256,4) caps VGPRs at 128 (no spill from unroll hoisting).
// ---------------------------------------------------------------------------
#define BM 32
#define GT 256

__global__ __launch_bounds__(GT, 4) void fused_gemm(
    const float* __restrict__ K,
    const _Float16* __restrict__ Bswz,
    const float* __restrict__ bias,
    float* __restrict__ out)
{
    __shared__ __align__(16) _Float16 Afrag[2 * KSTEPS * 512];   // 36,864 B

    const int tid  = threadIdx.x;
    const int bid  = blockIdx.x;
    const int row0 = (bid >> 1) * BM;
    const int cblk = bid & 1;                  // which 64-col half

    // --- features: 512 f-quads (32 rows x 16 quads), 2 per thread.
    // Thread loads 32 contiguous bytes of K (2x float4) -> 4 (x,y) pairs,
    // computes mag + Chebyshev harmonics, writes 9x ds_write_b64 per quad.
    #pragma unroll
    for (int it = 0; it < 2; ++it) {
        const int qi = tid + it * GT;
        const int n  = qi >> 4;                 // 0..31
        const int f0 = (qi & 15) * 4;           // 0,4,...,60
        const float* kp = K + (size_t)(row0 + n) * HEADD + 2 * f0;
        const float4 p0 = *(const float4*)kp;
        const float4 p1 = *(const float4*)(kp + 4);
        float xs[4] = {p0.x, p0.z, p1.x, p1.z};
        float ys[4] = {p0.y, p0.w, p1.y, p1.w};
        float mag[4], c1[4], s1[4], cc[4], sc[4], cp[4], sp[4];
        #pragma unroll
        for (int i = 0; i < 4; ++i) {
            float m2 = xs[i] * xs[i] + ys[i] * ys[i];
            float ri = (m2 > 0.f) ? rsqrtf(m2) : 0.f;
            mag[i] = m2 * ri; c1[i] = xs[i] * ri; s1[i] = ys[i] * ri;
            cp[i] = 1.f; sp[i] = 0.f; cc[i] = c1[i]; sc[i] = s1[i];
        }
        const int chunk = n >> 4, lc = n & 15;
        const int q = FRAG_Q(f0), j0 = FRAG_J(f0);      // j0 in {0,4}
        _Float16* base = Afrag + chunk * (KSTEPS * 512) + (q * 16 + lc) * 8 + j0;
        f16x4 v;
        #pragma unroll
        for (int i = 0; i < 4; ++i) v[i] = (_Float16)mag[i];
        *(f16x4*)(base + FRAG_KT(0, f0) * 512) = v;
        #pragma unroll
        for (int m = 1; m <= MHARM; ++m) {
            f16x4 vc, vs;
            #pragma unroll
            for (int i = 0; i < 4; ++i) {
                vc[i] = (_Float16)(mag[i] * cc[i]);
                vs[i] = (_Float16)(mag[i] * sc[i]);
            }
            *(f16x4*)(base + FRAG_KT(2 * m - 1, f0) * 512) = vc;
            *(f16x4*)(base + FRAG_KT(2 * m, f0)     * 512) = vs;
            #pragma unroll
            for (int i = 0; i < 4; ++i) {
                float cn = fmaf(2.f * c1[i], cc[i], -cp[i]);
                float sn = fmaf(2.f * c1[i], sc[i], -sp[i]);
                cp[i] = cc[i]; sp[i] = sc[i]; cc[i] = cn; sc[i] = sn;
            }
        }
    }
    __syncthreads();

    const int lane = tid & 63, wave = tid >> 6;        // 4 waves
    const int lc = lane & 15, q = lane >> 4;
    const int g = cblk * 4 + wave;                     // col group 0..7
    const int col = g * 16 + lc;

    f32x4 acc0 = {0.f, 0.f, 0.f, 0.f};
    f32x4 acc1 = {0.f, 0.f, 0.f, 0.f};

    const f16x8* bp  = (const f16x8*)Bswz + (size_t)g * KSTEPS * 64 + lane;
    const f16x8* ap0 = (const f16x8*)Afrag + lane;
    const f16x8* ap1 = ap0 + KSTEPS * 64;

    f16x8 b = bp[0];                                   // rotating prefetch
    #pragma unroll
    for (int kt = 0; kt < KSTEPS; ++kt) {
        f16x8 bn = b;
        if (kt + 1 < KSTEPS) bn = bp[(kt + 1) * 64];   // 1 KB burst per wave
        f16x8 a0 = ap0[kt * 64];                       // contiguous ds_read_b128
        f16x8 a1 = ap1[kt * 64];
        acc0 = __builtin_amdgcn_mfma_f32_16x16x32_f16(a0, b, acc0, 0, 0, 0);
        acc1 = __builtin_amdgcn_mfma_f32_16x16x32_f16(a1, b, acc1, 0, 0, 0);
        b = bn;
    }

    // C/D layout: col = lane&15, row = (lane>>4)*4 + reg
    const float bb = bias[col];
    #pragma unroll
    for (int j = 0; j < 4; ++j) {
        out[(size_t)(row0 + q * 4 + j) * NBINS + col]      = acc0[j] + bb;
        out[(size_t)(row0 + 16 + q * 4 + j) * NBINS + col] = acc1[j] + bb;
    }
}

// ---------------------------------------------------------------------------
// Fallback (ws too small for Bswz): direct form, inline trig.
// ---------------------------------------------------------------------------
#define KPB 16
#define FTHREADS 512
#define KPT 4
#define KV_STRIDE (KPB + 1)
#define LOG2E 1.44269504088896340736f

__global__ __launch_bounds__(FTHREADS) void vonmises_fallback(
    const float* __restrict__ K,
    const float* __restrict__ refang,
    const float* __restrict__ mu,
    const float* __restrict__ kappa,
    const float* __restrict__ weight,
    const float* __restrict__ bias,
    float* __restrict__ out)
{
    __shared__ float4 kvlds[NFREQ * KV_STRIDE];
    const int tid  = threadIdx.x;
    const int key0 = blockIdx.x * KPB;

    for (int p = tid; p < KPB * NFREQ; p += FTHREADS) {
        int key = p >> 6, f = p & (NFREQ - 1);
        const float2 xy = *(const float2*)(K + (size_t)(key0 + key) * HEADD + 2 * f);
        float m2 = xy.x * xy.x + xy.y * xy.y;
        float rm = (m2 > 0.f) ? rsqrtf(m2) : 0.f;
        kvlds[f * KV_STRIDE + key] = make_float4(xy.x * rm, xy.y * rm, m2 * rm, 0.f);
    }
    __syncthreads();

    const int bin = tid & (NBINS - 1);
    const int kbase = (tid >> 7) * KPT;
    float acc[KPT] = {0.f, 0.f, 0.f, 0.f};

    for (int f = 0; f < NFREQ; ++f) {
        float4 kv[KPT];
        #pragma unroll
        for (int j = 0; j < KPT; ++j) kv[j] = kvlds[f * KV_STRIDE + kbase + j];
        float wk[KPT] = {0.f, 0.f, 0.f, 0.f};
        #pragma unroll
        for (int k = 0; k < NKER; ++k) {
            int idx = (bin * NFREQ + f) * NKER + k;
            float me = mu[idx] + refang[f];
            float ka = kappa[idx] * LOG2E;
            float s, c;
            __sincosf(me, &s, &c);
            #pragma unroll
            for (int j = 0; j < KPT; ++j) {
                float t = fmaf(kv[j].x, ka * c, fmaf(kv[j].y, ka * s, -ka));
                wk[j] = fmaf(exp2f(t), weight[idx], wk[j]);
            }
        }
        #pragma unroll
        for (int j = 0; j < KPT; ++j) acc[j] = fmaf(wk[j], kv[j].z, acc[j]);
    }
    const float bb = bias[bin];
    #pragma unroll
    for (int j = 0; j < KPT; ++j)
        out[(size_t)(key0 + kbase + j) * NBINS + bin] = acc[j] + bb;
}

// ---------------------------------------------------------------------------
extern "C" void kernel_launch(void* const* d_in, const int* in_sizes, int n_in,
                              void* d_out, int out_size, void* d_ws, size_t ws_size,
                              hipStream_t stream) {
    const float* K      = (const float*)d_in[0];
    const float* refang = (const float*)d_in[1];
    const float* mu     = (const float*)d_in[2];
    const float* kappa  = (const float*)d_in[3];
    const float* weight = (const float*)d_in[4];
    const float* bias   = (const float*)d_in[5];
    float* out = (float*)d_out;

    const size_t need = (size_t)NBINS * KDIM * sizeof(_Float16);   // 144 KiB

    if (ws_size >= need) {
        _Float16* Bswz = (_Float16*)d_ws;
        build_coeffs<<<NBINS * NFREQ / 256, 256, 0, stream>>>(
            refang, mu, kappa, weight, Bswz);
        fused_gemm<<<(NKEYS / BM) * 2, GT, 0, stream>>>(K, Bswz, bias, out);
    } else {
        vonmises_fallback<<<NKEYS / KPB, FTHREADS, 0, stream>>>(
            K, refang, mu, kappa, weight, bias, out);
    }
}

// Round 6
// 15.648 us; speedup vs baseline: 3.5000x; 1.0338x over previous
//
#include <hip/hip_runtime.h>
#include <math.h>

#define NKEYS 8192
#define NBINS 128
#define NFREQ 64
#define NKER  3
#define HEADD 128

// Fourier expansion: e^{k(cos d - 1)} = e^-k [I0(k) + 2 sum_m Im(k) cos(m d)]
// kappa <= 1 -> M=4 truncation ~2e-4 relative; Bessel series j<=3 adds ~1e-6.
#define MHARM 4
#define NCH   9                    // {1, cos m, sin m}, m=1..4
#define KDIM  (NCH * NFREQ)        // 576
#define KSTEPS (KDIM / 32)         // 18 MFMA K-steps

// Fragment-order k-mapping (16x16x32 f16 MFMA, m89-verified):
//   k_global = kt*32 + q*8 + j  (q = lane>>4, j = 0..7)
//   (ch, f) <-> kt = ch*2 + (f>>5), q = (f>>3)&3, j = f&7   (bijective)
// Inverse: f = (kt&1)*32 + q*8 + j, ch = kt>>1.

#define BM 64                      // rows per block (4 chunks of 16)
#define GT 256                     // 4 waves; wave w -> 16 cols

typedef _Float16 f16x8 __attribute__((ext_vector_type(8)));
typedef float    f32x4 __attribute__((ext_vector_type(4)));

// ---------------------------------------------------------------------------
// Single fused kernel: A-features -> LDS (fragment order), B-coefficients
// recomputed IN REGISTERS per wave (48 terms/lane, no global table, no d_ws),
// then 18 K-steps of 16x16x32 f16 MFMA with B held in VGPRs.
// Block: 64 rows x 64 cols; grid = 128 row-groups x 2 col-halves = 256.
// ---------------------------------------------------------------------------
__global__ __launch_bounds__(GT, 2) void fused_all(
    const float* __restrict__ K,
    const float* __restrict__ refang,
    const float* __restrict__ mu,
    const float* __restrict__ kappa,
    const float* __restrict__ weight,
    const float* __restrict__ bias,
    float* __restrict__ out)
{
    __shared__ __align__(16) _Float16 Afrag[4 * KSTEPS * 512];   // 73,728 B

    const int tid  = threadIdx.x;
    const int bid  = blockIdx.x;
    const int row0 = (bid >> 1) * BM;
    const int cblk = bid & 1;                    // which 64-col half

    // ---------------- A prologue: 512 freq-octets, 2 per thread ------------
    // Thread handles 8 consecutive freqs of one row: 64 B of K (4x float4),
    // writes 9 ds_write_b128 (one per channel) in MFMA fragment order.
    #pragma unroll
    for (int it = 0; it < 2; ++it) {
        const int o  = tid + it * GT;
        const int n  = o >> 3, oc = o & 7;
        const int f0 = oc * 8;                   // 0,8,...,56
        const int qa = oc & 3, half = oc >> 2;
        const int chunk = n >> 4, lcn = n & 15;
        const float* kp = K + (size_t)(row0 + n) * HEADD + 2 * f0;
        const float4 p0 = ((const float4*)kp)[0];
        const float4 p1 = ((const float4*)kp)[1];
        const float4 p2 = ((const float4*)kp)[2];
        const float4 p3 = ((const float4*)kp)[3];
        float xs[8] = {p0.x, p0.z, p1.x, p1.z, p2.x, p2.z, p3.x, p3.z};
        float ys[8] = {p0.y, p0.w, p1.y, p1.w, p2.y, p2.w, p3.y, p3.w};
        float mag[8], c1[8], cc[8], sc[8], cp[8], sp[8];
        #pragma unroll
        for (int i = 0; i < 8; ++i) {
            float m2 = xs[i] * xs[i] + ys[i] * ys[i];
            float ri = (m2 > 0.f) ? rsqrtf(m2) : 0.f;
            mag[i] = m2 * ri;
            c1[i] = xs[i] * ri;
            float s1 = ys[i] * ri;
            cp[i] = 1.f; sp[i] = 0.f; cc[i] = c1[i]; sc[i] = s1;
        }
        // byte addr multiples of 16 throughout -> ds_write_b128 legal
        _Float16* base = Afrag + chunk * (KSTEPS * 512) + half * 512
                               + (qa * 16 + lcn) * 8;
        f16x8 v;
        #pragma unroll
        for (int i = 0; i < 8; ++i) v[i] = (_Float16)mag[i];
        *(f16x8*)base = v;                                   // ch 0 (kt = half)
        #pragma unroll
        for (int m = 1; m <= MHARM; ++m) {
            f16x8 vc, vs;
            #pragma unroll
            for (int i = 0; i < 8; ++i) {
                vc[i] = (_Float16)(mag[i] * cc[i]);
                vs[i] = (_Float16)(mag[i] * sc[i]);
            }
            *(f16x8*)(base + (2 * m - 1) * 1024) = vc;       // kt = (2m-1)*2+half
            *(f16x8*)(base + (2 * m) * 1024)     = vs;
            #pragma unroll
            for (int i = 0; i < 8; ++i) {
                float cn = fmaf(2.f * c1[i], cc[i], -cp[i]);
                float sn = fmaf(2.f * c1[i], sc[i], -sp[i]);
                cp[i] = cc[i]; sp[i] = sc[i]; cc[i] = cn; sc[i] = sn;
            }
        }
    }

    // ---------------- B coefficients in registers (48 terms/lane) ----------
    const int lane = tid & 63, wave = tid >> 6;
    const int q = lane >> 4, lc = lane & 15;
    const int g = cblk * 4 + wave;               // col group 0..7
    const int bin = g * 16 + lc;

    f16x8 bfrag[KSTEPS];
    #pragma unroll
    for (int half = 0; half < 2; ++half) {
        const int fb = half * 32 + q * 8;        // 8 consecutive freqs
        #pragma unroll
        for (int jq = 0; jq < 2; ++jq) {         // j-quads: limit reg pressure
            const size_t off = ((size_t)bin * NFREQ + fb + jq * 4) * NKER; // 16B-aligned
            const float4* mup = (const float4*)(mu + off);
            const float4* kpp = (const float4*)(kappa + off);
            const float4* wpp = (const float4*)(weight + off);
            float4 m4[3], k4[3], w4[3];          // 12 floats = 4 freqs x 3 kernels
            #pragma unroll
            for (int i = 0; i < 3; ++i) { m4[i] = mup[i]; k4[i] = kpp[i]; w4[i] = wpp[i]; }
            const float* mv = (const float*)m4;
            const float* kv = (const float*)k4;
            const float* wv = (const float*)w4;
            #pragma unroll
            for (int jj = 0; jj < 4; ++jj) {
                const int j = jq * 4 + jj;
                const float rf = refang[fb + j];
                float ach[NCH];
                #pragma unroll
                for (int c = 0; c < NCH; ++c) ach[c] = 0.f;
                #pragma unroll
                for (int k = 0; k < NKER; ++k) {
                    const float me  = mv[3 * jj + k] + rf;
                    const float kap = kv[3 * jj + k];
                    const float w   = wv[3 * jj + k];
                    const float wek = w * __expf(-kap);
                    float s1, c1;
                    __sincosf(me, &s1, &c1);
                    const float h = 0.5f * kap, h2 = h * h;
                    // I0 series (j<=3): 1 + h2 + h4/4 + h6/36
                    {
                        float t = h2, s = 1.f + t;
                        t *= h2 * 0.25f;              s += t;
                        t *= h2 * (1.f / 9.f);        s += t;
                        ach[0] = fmaf(wek, s, ach[0]);
                    }
                    float cc = c1, sc = s1, cp = 1.f, sp = 0.f;
                    float tm = h;                     // h^m/m!
                    #pragma unroll
                    for (int m = 1; m <= MHARM; ++m) {
                        float t = tm, s = tm;
                        t *= h2 * (1.f / (float)(1 * (m + 1))); s += t;
                        t *= h2 * (1.f / (float)(2 * (m + 2))); s += t;
                        t *= h2 * (1.f / (float)(3 * (m + 3))); s += t;
                        const float gm = 2.f * wek * s;
                        ach[2 * m - 1] = fmaf(gm, cc, ach[2 * m - 1]);
                        ach[2 * m]     = fmaf(gm, sc, ach[2 * m]);
                        const float cn = fmaf(2.f * c1, cc, -cp);
                        const float sn = fmaf(2.f * c1, sc, -sp);
                        cp = cc; sp = sc; cc = cn; sc = sn;
                        tm *= h * (1.f / (float)(m + 1));
                    }
                }
                #pragma unroll
                for (int c = 0; c < NCH; ++c)
                    bfrag[c * 2 + half][j] = (_Float16)ach[c];
            }
        }
    }

    __syncthreads();

    // ---------------- GEMM: 18 K-steps x 4 row-chunks, B in VGPRs ----------
    f32x4 acc[4] = {};
    const f16x8* ap = (const f16x8*)Afrag + lane;       // lane*16B, conflict-free
    #pragma unroll
    for (int kt = 0; kt < KSTEPS; ++kt) {
        #pragma unroll
        for (int c = 0; c < 4; ++c) {
            f16x8 a = ap[c * (KSTEPS * 64) + kt * 64];
            acc[c] = __builtin_amdgcn_mfma_f32_16x16x32_f16(a, bfrag[kt], acc[c], 0, 0, 0);
        }
    }

    // C/D layout: col = lane&15, row = (lane>>4)*4 + reg
    const int col = g * 16 + lc;
    const float bb = bias[col];
    #pragma unroll
    for (int c = 0; c < 4; ++c) {
        #pragma unroll
        for (int jj = 0; jj < 4; ++jj)
            out[(size_t)(row0 + c * 16 + q * 4 + jj) * NBINS + col] = acc[c][jj] + bb;
    }
}

// ---------------------------------------------------------------------------
extern "C" void kernel_launch(void* const* d_in, const int* in_sizes, int n_in,
                              void* d_out, int out_size, void* d_ws, size_t ws_size,
                              hipStream_t stream) {
    const float* K      = (const float*)d_in[0];
    const float* refang = (const float*)d_in[1];
    const float* mu     = (const float*)d_in[2];
    const float* kappa  = (const float*)d_in[3];
    const float* weight = (const float*)d_in[4];
    const float* bias   = (const float*)d_in[5];
    float* out = (float*)d_out;

    (void)d_ws; (void)ws_size; (void)in_sizes; (void)n_in; (void)out_size;

    fused_all<<<(NKEYS / BM) * 2, GT, 0, stream>>>(
        K, refang, mu, kappa, weight, bias, out);
}